// Round 3
// baseline (510.959 us; speedup 1.0000x reference)
//
#include <hip/hip_runtime.h>
#include <math.h>

static constexpr int IMGS = 2;
static constexpr int H = 128, W = 128;
static constexpr int NP = H * W;           // 16384
static constexpr int KWIN = 30;            // quickshift window radius (ceil(3*10))
static constexpr int GR = 20;              // gaussian radius int(4*5+0.5)
static constexpr float INV = 0.005f;       // 0.5 / (10*10)
static constexpr int MAXSEG = 40;

// padded feature layout: row stride 192 float4, cols [30,158) hold the image.
// float4 = (L, a, b, dens); pads = (1e6,1e6,1e6,-inf).
static constexpr int PSTR = 192;
static constexpr int PIMG = H * PSTR;      // 24576 float4 per image

// ---------------- rgb2lab (sRGB -> Lab, D65), CHW input -> float4 HW buffer ----
__global__ void k_lab(const float* __restrict__ x, float4* __restrict__ lab) {
#pragma clang fp contract(off)
  int i = blockIdx.x * blockDim.x + threadIdx.x;
  if (i >= IMGS * NP) return;
  int img = i / NP, p = i % NP;
  const float* base = x + img * 3 * NP;
  float rgb[3] = { base[p], base[NP + p], base[2 * NP + p] };
  float lin[3];
  for (int c = 0; c < 3; ++c) {
    float v = rgb[c];
    lin[c] = (v > 0.04045f) ? powf((v + 0.055f) / 1.055f, 2.4f) : (v / 12.92f);
  }
  const float M[3][3] = {{0.412453f, 0.357580f, 0.180423f},
                         {0.212671f, 0.715160f, 0.072169f},
                         {0.019334f, 0.119193f, 0.950227f}};
  const float wp[3] = {0.95047f, 1.0f, 1.08883f};
  float f[3];
  for (int j = 0; j < 3; ++j) {
    float s = lin[0] * M[j][0];
    s = s + lin[1] * M[j][1];
    s = s + lin[2] * M[j][2];
    float xyz = s / wp[j];
    f[j] = (xyz > 0.008856f) ? cbrtf(fmaxf(xyz, 1e-8f))
                             : (7.787f * xyz + (float)(16.0 / 116.0));
  }
  float L = 116.0f * f[1] - 16.0f;
  float a = 500.0f * (f[0] - f[1]);
  float b = 200.0f * (f[1] - f[2]);
  lab[i] = make_float4(L, a, b, 0.0f);
}

// ---------------- separable gaussian, symmetric padding ------------------------
// weight computation identical to round-1 (passed absmax 0.0) — do not touch
__device__ inline void load_weights(float* w) {
  if (threadIdx.x == 0) {
    double k[2 * GR + 1];
    double s = 0.0;
    for (int i = -GR; i <= GR; ++i) {
      double t = (double)i / 5.0;
      double v = exp(-0.5 * t * t);
      k[i + GR] = v;
      s += v;
    }
    for (int i = 0; i < 2 * GR + 1; ++i) w[i] = (float)(k[i] / s);
  }
  __syncthreads();
}

__global__ void k_blurV(const float4* __restrict__ in, float4* __restrict__ out) {
#pragma clang fp contract(off)
  __shared__ float w[2 * GR + 1];
  load_weights(w);
  int i = blockIdx.x * blockDim.x + threadIdx.x;
  if (i >= IMGS * NP) return;
  int img = i / NP, p = i % NP;
  int y = p / W, xx = p % W;
  float a0 = 0.0f, a1 = 0.0f, a2 = 0.0f;
  for (int t = 0; t <= 2 * GR; ++t) {
    int yy = y - GR + t;
    if (yy < 0) yy = -yy - 1;
    if (yy >= H) yy = 2 * H - 1 - yy;
    float4 v = in[img * NP + yy * W + xx];
    float wt = w[t];
    a0 = a0 + wt * v.x;
    a1 = a1 + wt * v.y;
    a2 = a2 + wt * v.z;
  }
  out[i] = make_float4(a0, a1, a2, 0.0f);
}

// writes into PADDED feature buffer (interior cols 30..157); .w=0 placeholder
__global__ void k_blurH(const float4* __restrict__ in, float4* __restrict__ pf) {
#pragma clang fp contract(off)
  __shared__ float w[2 * GR + 1];
  load_weights(w);
  int i = blockIdx.x * blockDim.x + threadIdx.x;
  if (i >= IMGS * NP) return;
  int img = i / NP, p = i % NP;
  int y = p / W, xx = p % W;
  float a0 = 0.0f, a1 = 0.0f, a2 = 0.0f;
  for (int t = 0; t <= 2 * GR; ++t) {
    int xq = xx - GR + t;
    if (xq < 0) xq = -xq - 1;
    if (xq >= W) xq = 2 * W - 1 - xq;
    float4 v = in[img * NP + y * W + xq];
    float wt = w[t];
    a0 = a0 + wt * v.x;
    a1 = a1 + wt * v.y;
    a2 = a2 + wt * v.z;
  }
  pf[img * PIMG + y * PSTR + (xx + KWIN)] = make_float4(a0, a1, a2, 0.0f);
}

// ---------------- pad fill: xyz sentinel 1e6 (exp term -> exact +0.0),
//                  .w sentinel -inf (density pad, never qualifies as parent) ---
__global__ void k_fillPF(float4* __restrict__ pf) {
  int i = blockIdx.x * blockDim.x + threadIdx.x;
  if (i < IMGS * PIMG) pf[i] = make_float4(1e6f, 1e6f, 1e6f, -__builtin_inff());
}

// ---------------- density: LDS row staging, sequential row-major sum -----------
// one wave per block; block = (img, y, 64-px tile). dens written into pf.w
// (no k_dens thread reads .w, so the concurrent write is benign).
__global__ __launch_bounds__(64, 1)
void k_dens(float4* __restrict__ pf) {
#pragma clang fp contract(off)
  __shared__ float4 lds[2][128];
  int b = blockIdx.x;                 // 512 blocks: img*256 + y*2 + tile
  int lane = threadIdx.x;
  int tile = b & 1;
  int y = (b >> 1) & 127;
  int img = b >> 8;
  int x0 = tile * 64;
  int x = x0 + lane;
  float4* fimg = pf + img * PIMG;
  float4 fc = fimg[y * PSTR + (x + KWIN)];
  int ny0 = (y - KWIN < 0) ? 0 : y - KWIN;
  int ny1 = (y + KWIN > H - 1) ? H - 1 : y + KWIN;

  // stage first row: padded cols x0 .. x0+127  (= image cols x0-30 .. x0+97)
  {
    const float4* row = fimg + ny0 * PSTR + x0;
    lds[0][lane] = row[lane];
    lds[0][lane + 64] = row[lane + 64];
  }
  float acc = 0.0f;
  int cur = 0;
  for (int ny = ny0; ny <= ny1; ++ny) {   // wave-uniform; skipped rows add exact 0.0
    float4 p0, p1;
    if (ny < ny1) {                        // prefetch next row early (latency hidden)
      const float4* nrow = fimg + (ny + 1) * PSTR + x0;
      p0 = nrow[lane];
      p1 = nrow[lane + 64];
    }
    int dr = ny - y;
    int spr = dr * dr;
    const float4* l = &lds[cur][lane];     // l[dc+30] = neighbor at col x+dc
#pragma unroll
    for (int dc = -KWIN; dc <= KWIN; ++dc) {
      float4 nb = l[dc + KWIN];
      float d0 = fc.x - nb.x, d1 = fc.y - nb.y, d2 = fc.z - nb.z;
      float d = (d0 * d0 + d1 * d1) + d2 * d2;
      d = d + (float)(spr + dc * dc);
      acc = acc + expf(-d * INV);          // pad cols: d~3e12 -> exp == +0.0 exactly
    }
    if (ny < ny1) {
      lds[cur ^ 1][lane] = p0;
      lds[cur ^ 1][lane + 64] = p1;
      cur ^= 1;
    }
  }
  fimg[y * PSTR + (x + KWIN)].w = acc;     // 4B store of density into .w
}

// ---------------- parent: LDS row staging, nearest strictly-higher density -----
__global__ __launch_bounds__(64, 1)
void k_par(const float4* __restrict__ pf, int* __restrict__ parent) {
#pragma clang fp contract(off)
  __shared__ float4 lds[2][128];
  int b = blockIdx.x;
  int lane = threadIdx.x;
  int tile = b & 1;
  int y = (b >> 1) & 127;
  int img = b >> 8;
  int x0 = tile * 64;
  int x = x0 + lane;
  const float4* fimg = pf + img * PIMG;
  float4 fc = fimg[y * PSTR + (x + KWIN)];
  float dcen = fc.w;
  int ny0 = (y - KWIN < 0) ? 0 : y - KWIN;
  int ny1 = (y + KWIN > H - 1) ? H - 1 : y + KWIN;

  {
    const float4* row = fimg + ny0 * PSTR + x0;
    lds[0][lane] = row[lane];
    lds[0][lane + 64] = row[lane + 64];
  }
  float bestd = __builtin_inff();
  int bestp = y * W + x;
  int cur = 0;
  for (int ny = ny0; ny <= ny1; ++ny) {    // rows outside image: ref nd=-inf, never qualify
    float4 p0, p1;
    if (ny < ny1) {
      const float4* nrow = fimg + (ny + 1) * PSTR + x0;
      p0 = nrow[lane];
      p1 = nrow[lane + 64];
    }
    int dr = ny - y;
    int spr = dr * dr;
    int qbase = ny * W + x;
    const float4* l = &lds[cur][lane];
#pragma unroll
    for (int dc = -KWIN; dc <= KWIN; ++dc) {
      float4 nb = l[dc + KWIN];
      float nd = nb.w;                     // pad cols: -inf
      float d0 = fc.x - nb.x, d1 = fc.y - nb.y, d2 = fc.z - nb.z;
      float d = (d0 * d0 + d1 * d1) + d2 * d2;
      d = d + (float)(spr + dc * dc);
      int better = (nd > dcen) & (d < bestd);  // strict <: first-in-row-major wins ties
      bestd = better ? d : bestd;
      bestp = better ? (qbase + dc) : bestp;
    }
    if (ny < ny1) {
      lds[cur ^ 1][lane] = p0;
      lds[cur ^ 1][lane + 64] = p1;
      cur ^= 1;
    }
  }
  if (bestd > 400.0f) bestp = y * W + x;   // sqrt(best_d) > max_dist
  parent[(img * NP) + y * W + x] = bestp;
}

// ---------------- root chase + presence marking --------------------------------
__global__ void k_root(const int* __restrict__ parent, int* __restrict__ root,
                       int* __restrict__ pres) {
  int i = blockIdx.x * blockDim.x + threadIdx.x;
  if (i >= IMGS * NP) return;
  int img = i / NP, p = i % NP;
  const int* par = parent + img * NP;
  int r = par[p];
  for (int it = 0; it < NP; ++it) {        // chains strictly increase density => acyclic
    int pr = par[r];
    if (pr == r) break;
    r = pr;
  }
  root[i] = r;
  pres[img * NP + r] = 1;
}

// ---------------- per-image inclusive scan of presence flags -------------------
__global__ void k_scan(int* __restrict__ pres) {
  __shared__ int part[256];
  int img = blockIdx.x;
  int t = threadIdx.x;                     // 256 threads x 64 elements
  int* a = pres + img * NP;
  int base = t * 64;
  int s = 0;
  for (int j = 0; j < 64; ++j) s += a[base + j];
  part[t] = s;
  __syncthreads();
  for (int off = 1; off < 256; off <<= 1) {
    int add = (t >= off) ? part[t - off] : 0;
    __syncthreads();
    part[t] += add;
    __syncthreads();
  }
  int run = part[t] - s;
  for (int j = 0; j < 64; ++j) {
    run += a[base + j];
    a[base + j] = run;
  }
}

// ---------------- final labels --------------------------------------------------
__global__ void k_label(const int* __restrict__ root, const int* __restrict__ cums,
                        int* __restrict__ out) {
  int i = blockIdx.x * blockDim.x + threadIdx.x;
  if (i >= IMGS * NP) return;
  int img = i / NP;
  int r = root[i];
  int lab = cums[img * NP + r] - 1;
  out[i] = (lab < MAXSEG - 1) ? lab : (MAXSEG - 1);
}

extern "C" void kernel_launch(void* const* d_in, const int* in_sizes, int n_in,
                              void* d_out, int out_size, void* d_ws, size_t ws_size,
                              hipStream_t stream) {
  const float* x = (const float*)d_in[0];
  int* out = (int*)d_out;
  char* ws = (char*)d_ws;

  // workspace layout (~1.75 MB); parent/root/pres alias bufA (dead after blurV)
  float4* pf   = (float4*)(ws);                         // 2*24576*16 = 786432
  float4* bufA = (float4*)(ws + 786432);                // 524288 (lab out / blurV in)
  float4* bufB = (float4*)(ws + 786432 + 524288);       // 524288 (blurV out / blurH in)
  int* parent  = (int*)(ws + 786432);                   // alias bufA
  int* root    = (int*)(ws + 786432 + 131072);
  int* pres    = (int*)(ws + 786432 + 262144);

  const int total = IMGS * NP;                          // 32768
  const int ptotal = IMGS * PIMG;                       // 49152

  k_fillPF<<<(ptotal + 255) / 256, 256, 0, stream>>>(pf);
  k_lab<<<total / 256, 256, 0, stream>>>(x, bufA);
  k_blurV<<<total / 256, 256, 0, stream>>>(bufA, bufB);
  k_blurH<<<total / 256, 256, 0, stream>>>(bufB, pf);
  k_dens<<<512, 64, 0, stream>>>(pf);
  k_par<<<512, 64, 0, stream>>>(pf, parent);
  hipMemsetAsync(pres, 0, total * sizeof(int), stream);
  k_root<<<total / 256, 256, 0, stream>>>(parent, root, pres);
  k_scan<<<IMGS, 256, 0, stream>>>(pres);
  k_label<<<total / 256, 256, 0, stream>>>(root, pres, out);
}

// Round 4
// 270.445 us; speedup vs baseline: 1.8893x; 1.8893x over previous
//
#include <hip/hip_runtime.h>
#include <math.h>

static constexpr int IMGS = 2;
static constexpr int H = 128, W = 128;
static constexpr int NP = H * W;           // 16384
static constexpr int KWIN = 30;            // quickshift window radius (ceil(3*10))
static constexpr int GR = 20;              // gaussian radius int(4*5+0.5)
static constexpr float INV = 0.005f;       // 0.5 / (10*10)
static constexpr int MAXSEG = 40;

// padded feature layout: row stride 192 float4, cols [30,158) hold the image.
// float4 = (L, a, b, dens); pads = (1e6,1e6,1e6,-inf).
static constexpr int PSTR = 192;
static constexpr int PIMG = H * PSTR;      // 24576 float4 per image

// ---------------- rgb2lab (sRGB -> Lab, D65), CHW input -> float4 HW buffer ----
__global__ void k_lab(const float* __restrict__ x, float4* __restrict__ lab) {
#pragma clang fp contract(off)
  int i = blockIdx.x * blockDim.x + threadIdx.x;
  if (i >= IMGS * NP) return;
  int img = i / NP, p = i % NP;
  const float* base = x + img * 3 * NP;
  float rgb[3] = { base[p], base[NP + p], base[2 * NP + p] };
  float lin[3];
  for (int c = 0; c < 3; ++c) {
    float v = rgb[c];
    lin[c] = (v > 0.04045f) ? powf((v + 0.055f) / 1.055f, 2.4f) : (v / 12.92f);
  }
  const float M[3][3] = {{0.412453f, 0.357580f, 0.180423f},
                         {0.212671f, 0.715160f, 0.072169f},
                         {0.019334f, 0.119193f, 0.950227f}};
  const float wp[3] = {0.95047f, 1.0f, 1.08883f};
  float f[3];
  for (int j = 0; j < 3; ++j) {
    float s = lin[0] * M[j][0];
    s = s + lin[1] * M[j][1];
    s = s + lin[2] * M[j][2];
    float xyz = s / wp[j];
    f[j] = (xyz > 0.008856f) ? cbrtf(fmaxf(xyz, 1e-8f))
                             : (7.787f * xyz + (float)(16.0 / 116.0));
  }
  float L = 116.0f * f[1] - 16.0f;
  float a = 500.0f * (f[0] - f[1]);
  float b = 200.0f * (f[1] - f[2]);
  lab[i] = make_float4(L, a, b, 0.0f);
}

// ---------------- separable gaussian, symmetric padding ------------------------
// weight computation identical to round-1 (passed absmax 0.0) — do not touch
__device__ inline void load_weights(float* w) {
  if (threadIdx.x == 0) {
    double k[2 * GR + 1];
    double s = 0.0;
    for (int i = -GR; i <= GR; ++i) {
      double t = (double)i / 5.0;
      double v = exp(-0.5 * t * t);
      k[i + GR] = v;
      s += v;
    }
    for (int i = 0; i < 2 * GR + 1; ++i) w[i] = (float)(k[i] / s);
  }
  __syncthreads();
}

__global__ void k_blurV(const float4* __restrict__ in, float4* __restrict__ out) {
#pragma clang fp contract(off)
  __shared__ float w[2 * GR + 1];
  load_weights(w);
  int i = blockIdx.x * blockDim.x + threadIdx.x;
  if (i >= IMGS * NP) return;
  int img = i / NP, p = i % NP;
  int y = p / W, xx = p % W;
  float a0 = 0.0f, a1 = 0.0f, a2 = 0.0f;
  for (int t = 0; t <= 2 * GR; ++t) {
    int yy = y - GR + t;
    if (yy < 0) yy = -yy - 1;
    if (yy >= H) yy = 2 * H - 1 - yy;
    float4 v = in[img * NP + yy * W + xx];
    float wt = w[t];
    a0 = a0 + wt * v.x;
    a1 = a1 + wt * v.y;
    a2 = a2 + wt * v.z;
  }
  out[i] = make_float4(a0, a1, a2, 0.0f);
}

// writes into PADDED feature buffer (interior cols 30..157); .w=0 placeholder
__global__ void k_blurH(const float4* __restrict__ in, float4* __restrict__ pf) {
#pragma clang fp contract(off)
  __shared__ float w[2 * GR + 1];
  load_weights(w);
  int i = blockIdx.x * blockDim.x + threadIdx.x;
  if (i >= IMGS * NP) return;
  int img = i / NP, p = i % NP;
  int y = p / W, xx = p % W;
  float a0 = 0.0f, a1 = 0.0f, a2 = 0.0f;
  for (int t = 0; t <= 2 * GR; ++t) {
    int xq = xx - GR + t;
    if (xq < 0) xq = -xq - 1;
    if (xq >= W) xq = 2 * W - 1 - xq;
    float4 v = in[img * NP + y * W + xq];
    float wt = w[t];
    a0 = a0 + wt * v.x;
    a1 = a1 + wt * v.y;
    a2 = a2 + wt * v.z;
  }
  pf[img * PIMG + y * PSTR + (xx + KWIN)] = make_float4(a0, a1, a2, 0.0f);
}

// ---------------- pad fill: xyz sentinel 1e6 (exp term -> exact +0.0),
//                  .w sentinel -inf (density pad, never qualifies as parent) ---
__global__ void k_fillPF(float4* __restrict__ pf) {
  int i = blockIdx.x * blockDim.x + threadIdx.x;
  if (i < IMGS * PIMG) pf[i] = make_float4(1e6f, 1e6f, 1e6f, -__builtin_inff());
}

// ---------------- density: producer/consumer, exact sequential fold ------------
// block = 4 waves per 64-px tile. All waves produce exp terms (dc-partitioned
// 8/18/18/17; wave0 gets fewer since it also folds). Wave0 folds each row's 61
// terms in exact (row, dc) order. Wave3 additionally stages the next feature
// row. One barrier per row; double-buffered rowbuf+termbuf make it race-free:
// producers can only overwrite buf[k&1] after barrier k+1, which wave0 reaches
// only after fold(k).
__global__ __launch_bounds__(256, 2)
void k_dens(float4* __restrict__ pf) {
#pragma clang fp contract(off)
  __shared__ float4 rowbuf[2][128];
  __shared__ float termbuf[2][61][64];
  int tid = threadIdx.x;
  int lane = tid & 63;
  int wave = tid >> 6;
  int b = blockIdx.x;                      // 512 blocks: img*256 + y*2 + tile
  int tile = b & 1, y = (b >> 1) & 127, img = b >> 8;
  int x0 = tile * 64;
  float4* fimg = pf + img * PIMG;
  float4 fc = fimg[y * PSTR + x0 + lane + KWIN];
  int ny0 = y - KWIN; if (ny0 < 0) ny0 = 0;
  int ny1 = y + KWIN; if (ny1 > H - 1) ny1 = H - 1;
  int db = (wave == 0) ? 0 : (wave == 1) ? 8 : (wave == 2) ? 26 : 44;
  int de = (wave == 0) ? 8 : (wave == 1) ? 26 : (wave == 2) ? 44 : 61;
  if (wave == 3) {
    const float4* row = fimg + ny0 * PSTR + x0;
    rowbuf[0][lane] = row[lane];
    rowbuf[0][lane + 64] = row[lane + 64];
  }
  __syncthreads();
  float acc = 0.0f;
  for (int ny = ny0; ny <= ny1; ++ny) {    // skipped rows: ref adds exact 0.0
    int kb = (ny - ny0) & 1;
    if (wave == 3 && ny < ny1) {
      const float4* nrow = fimg + (ny + 1) * PSTR + x0;
      rowbuf[kb ^ 1][lane] = nrow[lane];
      rowbuf[kb ^ 1][lane + 64] = nrow[lane + 64];
    }
    int dr = ny - y, spr = dr * dr;
    for (int dcu = db; dcu < de; ++dcu) {
      float4 nb = rowbuf[kb][lane + dcu];
      float d0 = fc.x - nb.x, d1 = fc.y - nb.y, d2 = fc.z - nb.z;
      float d = (d0 * d0 + d1 * d1) + d2 * d2;
      int dc = dcu - KWIN;
      d = d + (float)(spr + dc * dc);
      termbuf[kb][dcu][lane] = expf(-d * INV);  // pad cols -> exact +0.0
    }
    __syncthreads();
    if (wave == 0) {
#pragma unroll
      for (int dcu = 0; dcu < 61; ++dcu)
        acc = acc + termbuf[kb][dcu][lane];     // exact reference order
    }
  }
  if (wave == 0) fimg[y * PSTR + x0 + lane + KWIN].w = acc;
}

// ---------------- parent: 4-wave exact-parallel argmin -------------------------
// Window rows block-partitioned across waves: wave w's (dr,dc) ranks strictly
// precede wave w+1's. Within a wave, sequential (dr asc, dc asc) with strict <.
// Cross-wave merge in wave order with strict < keeps the earliest rank — exact
// reproduction of the reference's first-in-row-major tie-break. No fp
// reassociation anywhere.
__global__ __launch_bounds__(256, 2)
void k_par(const float4* __restrict__ pf, int* __restrict__ parent) {
#pragma clang fp contract(off)
  __shared__ float4 prow[4][2][128];
  __shared__ float m_d[4][64];
  __shared__ int   m_p[4][64];
  int tid = threadIdx.x, lane = tid & 63, wave = tid >> 6;
  int b = blockIdx.x;
  int tile = b & 1, y = (b >> 1) & 127, img = b >> 8;
  int x0 = tile * 64, x = x0 + lane;
  const float4* fimg = pf + img * PIMG;
  float4 fc = fimg[y * PSTR + x + KWIN];
  float dcen = fc.w;
  int ny0 = y - KWIN; if (ny0 < 0) ny0 = 0;
  int ny1 = y + KWIN; if (ny1 > H - 1) ny1 = H - 1;
  int nrows = ny1 - ny0 + 1;
  int chunk = (nrows + 3) >> 2;
  int rb = ny0 + wave * chunk;
  int re = rb + chunk; if (re > ny1 + 1) re = ny1 + 1;
  float bestd = __builtin_inff();
  int bestp = y * W + x;
  if (rb < re) {
    const float4* row = fimg + rb * PSTR + x0;
    prow[wave][0][lane] = row[lane];
    prow[wave][0][lane + 64] = row[lane + 64];
    int cur = 0;
    for (int ny = rb; ny < re; ++ny) {
      float4 p0, p1;
      if (ny + 1 < re) {
        const float4* nrow = fimg + (ny + 1) * PSTR + x0;
        p0 = nrow[lane];
        p1 = nrow[lane + 64];
      }
      int dr = ny - y, spr = dr * dr;
      int qbase = ny * W + x;
#pragma unroll
      for (int dcu = 0; dcu < 61; ++dcu) {
        float4 nb = prow[wave][cur][lane + dcu];
        float nd = nb.w;                   // pad cols: -inf, never qualifies
        float d0 = fc.x - nb.x, d1 = fc.y - nb.y, d2 = fc.z - nb.z;
        float d = (d0 * d0 + d1 * d1) + d2 * d2;
        int dc = dcu - KWIN;
        d = d + (float)(spr + dc * dc);
        int better = (nd > dcen) & (d < bestd);
        bestd = better ? d : bestd;
        bestp = better ? (qbase + dc) : bestp;
      }
      if (ny + 1 < re) {
        prow[wave][cur ^ 1][lane] = p0;
        prow[wave][cur ^ 1][lane + 64] = p1;
        cur ^= 1;
      }
    }
  }
  m_d[wave][lane] = bestd;
  m_p[wave][lane] = bestp;
  __syncthreads();
  if (wave == 0) {
    for (int w = 1; w < 4; ++w) {
      float dw = m_d[w][lane];
      int pw = m_p[w][lane];
      int better = dw < bestd;             // ties keep earlier wave = lower rank
      bestd = better ? dw : bestd;
      bestp = better ? pw : bestp;
    }
    if (bestd > 400.0f) bestp = y * W + x; // sqrt(best_d) > max_dist
    parent[img * NP + y * W + x] = bestp;
  }
}

// ---------------- root chase + presence marking --------------------------------
__global__ void k_root(const int* __restrict__ parent, int* __restrict__ root,
                       int* __restrict__ pres) {
  int i = blockIdx.x * blockDim.x + threadIdx.x;
  if (i >= IMGS * NP) return;
  int img = i / NP, p = i % NP;
  const int* par = parent + img * NP;
  int r = par[p];
  for (int it = 0; it < NP; ++it) {        // chains strictly increase density => acyclic
    int pr = par[r];
    if (pr == r) break;
    r = pr;
  }
  root[i] = r;
  pres[img * NP + r] = 1;
}

// ---------------- per-image inclusive scan of presence flags -------------------
__global__ void k_scan(int* __restrict__ pres) {
  __shared__ int part[256];
  int img = blockIdx.x;
  int t = threadIdx.x;                     // 256 threads x 64 elements
  int* a = pres + img * NP;
  int base = t * 64;
  int s = 0;
  for (int j = 0; j < 64; ++j) s += a[base + j];
  part[t] = s;
  __syncthreads();
  for (int off = 1; off < 256; off <<= 1) {
    int add = (t >= off) ? part[t - off] : 0;
    __syncthreads();
    part[t] += add;
    __syncthreads();
  }
  int run = part[t] - s;
  for (int j = 0; j < 64; ++j) {
    run += a[base + j];
    a[base + j] = run;
  }
}

// ---------------- final labels --------------------------------------------------
__global__ void k_label(const int* __restrict__ root, const int* __restrict__ cums,
                        int* __restrict__ out) {
  int i = blockIdx.x * blockDim.x + threadIdx.x;
  if (i >= IMGS * NP) return;
  int img = i / NP;
  int r = root[i];
  int lab = cums[img * NP + r] - 1;
  out[i] = (lab < MAXSEG - 1) ? lab : (MAXSEG - 1);
}

extern "C" void kernel_launch(void* const* d_in, const int* in_sizes, int n_in,
                              void* d_out, int out_size, void* d_ws, size_t ws_size,
                              hipStream_t stream) {
  const float* x = (const float*)d_in[0];
  int* out = (int*)d_out;
  char* ws = (char*)d_ws;

  // workspace layout (~1.75 MB); parent/root/pres alias bufA (dead after blurV)
  float4* pf   = (float4*)(ws);                         // 2*24576*16 = 786432
  float4* bufA = (float4*)(ws + 786432);                // 524288 (lab out / blurV in)
  float4* bufB = (float4*)(ws + 786432 + 524288);       // 524288 (blurV out / blurH in)
  int* parent  = (int*)(ws + 786432);                   // alias bufA
  int* root    = (int*)(ws + 786432 + 131072);
  int* pres    = (int*)(ws + 786432 + 262144);

  const int total = IMGS * NP;                          // 32768
  const int ptotal = IMGS * PIMG;                       // 49152

  k_fillPF<<<(ptotal + 255) / 256, 256, 0, stream>>>(pf);
  k_lab<<<total / 256, 256, 0, stream>>>(x, bufA);
  k_blurV<<<total / 256, 256, 0, stream>>>(bufA, bufB);
  k_blurH<<<total / 256, 256, 0, stream>>>(bufB, pf);
  k_dens<<<512, 256, 0, stream>>>(pf);
  k_par<<<512, 256, 0, stream>>>(pf, parent);
  hipMemsetAsync(pres, 0, total * sizeof(int), stream);
  k_root<<<total / 256, 256, 0, stream>>>(parent, root, pres);
  k_scan<<<IMGS, 256, 0, stream>>>(pres);
  k_label<<<total / 256, 256, 0, stream>>>(root, pres, out);
}

// Round 6
// 242.400 us; speedup vs baseline: 2.1079x; 1.1157x over previous
//
#include <hip/hip_runtime.h>
#include <math.h>

static constexpr int IMGS = 2;
static constexpr int H = 128, W = 128;
static constexpr int NP = H * W;           // 16384
static constexpr int KWIN = 30;            // quickshift window radius (ceil(3*10))
static constexpr int GR = 20;              // gaussian radius int(4*5+0.5)
static constexpr float INV = 0.005f;       // 0.5 / (10*10)
static constexpr int MAXSEG = 40;

// padded feature layout: row stride 192 float4, cols [30,158) hold the image.
// float4 = (L, a, b, dens); pads = (1e6,1e6,1e6,-inf).
static constexpr int PSTR = 192;
static constexpr int PIMG = H * PSTR;      // 24576 float4 per image

// ---------------- rgb2lab (sRGB -> Lab, D65), CHW input -> float4 HW buffer ----
__global__ void k_lab(const float* __restrict__ x, float4* __restrict__ lab) {
#pragma clang fp contract(off)
  int i = blockIdx.x * blockDim.x + threadIdx.x;
  if (i >= IMGS * NP) return;
  int img = i / NP, p = i % NP;
  const float* base = x + img * 3 * NP;
  float rgb[3] = { base[p], base[NP + p], base[2 * NP + p] };
  float lin[3];
  for (int c = 0; c < 3; ++c) {
    float v = rgb[c];
    lin[c] = (v > 0.04045f) ? powf((v + 0.055f) / 1.055f, 2.4f) : (v / 12.92f);
  }
  const float M[3][3] = {{0.412453f, 0.357580f, 0.180423f},
                         {0.212671f, 0.715160f, 0.072169f},
                         {0.019334f, 0.119193f, 0.950227f}};
  const float wp[3] = {0.95047f, 1.0f, 1.08883f};
  float f[3];
  for (int j = 0; j < 3; ++j) {
    float s = lin[0] * M[j][0];
    s = s + lin[1] * M[j][1];
    s = s + lin[2] * M[j][2];
    float xyz = s / wp[j];
    f[j] = (xyz > 0.008856f) ? cbrtf(fmaxf(xyz, 1e-8f))
                             : (7.787f * xyz + (float)(16.0 / 116.0));
  }
  float L = 116.0f * f[1] - 16.0f;
  float a = 500.0f * (f[0] - f[1]);
  float b = 200.0f * (f[1] - f[2]);
  lab[i] = make_float4(L, a, b, 0.0f);
}

// ---------------- separable gaussian, symmetric padding ------------------------
// weight computation identical to round-1 (passed absmax 0.0) — do not touch
__device__ inline void load_weights(float* w) {
  if (threadIdx.x == 0) {
    double k[2 * GR + 1];
    double s = 0.0;
    for (int i = -GR; i <= GR; ++i) {
      double t = (double)i / 5.0;
      double v = exp(-0.5 * t * t);
      k[i + GR] = v;
      s += v;
    }
    for (int i = 0; i < 2 * GR + 1; ++i) w[i] = (float)(k[i] / s);
  }
  __syncthreads();
}

__global__ void k_blurV(const float4* __restrict__ in, float4* __restrict__ out) {
#pragma clang fp contract(off)
  __shared__ float w[2 * GR + 1];
  load_weights(w);
  int i = blockIdx.x * blockDim.x + threadIdx.x;
  if (i >= IMGS * NP) return;
  int img = i / NP, p = i % NP;
  int y = p / W, xx = p % W;
  float a0 = 0.0f, a1 = 0.0f, a2 = 0.0f;
  for (int t = 0; t <= 2 * GR; ++t) {
    int yy = y - GR + t;
    if (yy < 0) yy = -yy - 1;
    if (yy >= H) yy = 2 * H - 1 - yy;
    float4 v = in[img * NP + yy * W + xx];
    float wt = w[t];
    a0 = a0 + wt * v.x;
    a1 = a1 + wt * v.y;
    a2 = a2 + wt * v.z;
  }
  out[i] = make_float4(a0, a1, a2, 0.0f);
}

// writes into PADDED feature buffer (interior cols 30..157)
__global__ void k_blurH(const float4* __restrict__ in, float4* __restrict__ pf) {
#pragma clang fp contract(off)
  __shared__ float w[2 * GR + 1];
  load_weights(w);
  int i = blockIdx.x * blockDim.x + threadIdx.x;
  if (i >= IMGS * NP) return;
  int img = i / NP, p = i % NP;
  int y = p / W, xx = p % W;
  float a0 = 0.0f, a1 = 0.0f, a2 = 0.0f;
  for (int t = 0; t <= 2 * GR; ++t) {
    int xq = xx - GR + t;
    if (xq < 0) xq = -xq - 1;
    if (xq >= W) xq = 2 * W - 1 - xq;
    float4 v = in[img * NP + y * W + xq];
    float wt = w[t];
    a0 = a0 + wt * v.x;
    a1 = a1 + wt * v.y;
    a2 = a2 + wt * v.z;
  }
  pf[img * PIMG + y * PSTR + (xx + KWIN)] = make_float4(a0, a1, a2, 0.0f);
}

// ---------------- fill: pf sentinels only --------------------------------------
// xyz sentinel 1e6 (exp term -> exact +0.0); .w sentinel -inf (density pad).
// NOTE: pres must NOT be zeroed here — pres aliases bufA, which k_lab writes
// AFTER this kernel (R5 bug). pres is memset right before k_root instead.
__global__ void k_fill(float4* __restrict__ pf) {
  int i = blockIdx.x * blockDim.x + threadIdx.x;
  if (i < IMGS * PIMG) pf[i] = make_float4(1e6f, 1e6f, 1e6f, -__builtin_inff());
}

// ---------------- density: 8-wave producer/folder, exact sequential fold -------
// wave0: folds each row's 61 terms in exact (row, dc) order.
// waves 1..7: produce dc-chunks 9/9/9/9/9/8/8 (template-unrolled, immediate
// LDS offsets). wave7 also prefetches the next feature row.
// Double-buffered rowbuf+termbuf, one barrier per row — race-free: producers
// can only overwrite termbuf[k&1] after barrier k+1, which wave0 reaches only
// after fold(k); rowbuf[kb^1] is written before barrier k and read after it.
template<int DB, int DE>
__device__ inline void produce_terms(const float4* __restrict__ rb,
                                     float* __restrict__ tb,
                                     float4 fc, float sprf, int lane) {
#pragma clang fp contract(off)
#pragma unroll
  for (int dcu = DB; dcu < DE; ++dcu) {
    float4 nb = rb[lane + dcu];
    float d0 = fc.x - nb.x, d1 = fc.y - nb.y, d2 = fc.z - nb.z;
    float d = (d0 * d0 + d1 * d1) + d2 * d2;
    float cdc = (float)((dcu - KWIN) * (dcu - KWIN));
    d = d + (sprf + cdc);                 // exact: both ints < 2^11, sum exact
    tb[dcu * 64 + lane] = expf(-d * INV); // pad cols -> exact +0.0
  }
}

__global__ __launch_bounds__(512, 4)
void k_dens(float4* __restrict__ pf) {
#pragma clang fp contract(off)
  __shared__ float4 rowbuf[2][128];
  __shared__ float termbuf[2][61][64];
  int tid = threadIdx.x;
  int lane = tid & 63;
  int wave = tid >> 6;
  int b = blockIdx.x;                      // 512 blocks: img*256 + y*2 + tile
  int tile = b & 1, y = (b >> 1) & 127, img = b >> 8;
  int x0 = tile * 64;
  float4* fimg = pf + img * PIMG;
  float4 fc = fimg[y * PSTR + x0 + lane + KWIN];
  int ny0 = y - KWIN; if (ny0 < 0) ny0 = 0;
  int ny1 = y + KWIN; if (ny1 > H - 1) ny1 = H - 1;
  if (wave == 7) {
    const float4* row = fimg + ny0 * PSTR + x0;
    rowbuf[0][lane] = row[lane];
    rowbuf[0][lane + 64] = row[lane + 64];
  }
  __syncthreads();
  float acc = 0.0f;
  for (int ny = ny0; ny <= ny1; ++ny) {    // skipped rows: ref adds exact 0.0
    int kb = (ny - ny0) & 1;
    float4 p0, p1;
    bool pre = (wave == 7) && (ny < ny1);
    if (pre) {                             // issue prefetch early
      const float4* nrow = fimg + (ny + 1) * PSTR + x0;
      p0 = nrow[lane];
      p1 = nrow[lane + 64];
    }
    int dr = ny - y;
    float sprf = (float)(dr * dr);
    const float4* rb = rowbuf[kb];
    float* tb = &termbuf[kb][0][0];
    if      (wave == 1) produce_terms< 0,  9>(rb, tb, fc, sprf, lane);
    else if (wave == 2) produce_terms< 9, 18>(rb, tb, fc, sprf, lane);
    else if (wave == 3) produce_terms<18, 27>(rb, tb, fc, sprf, lane);
    else if (wave == 4) produce_terms<27, 36>(rb, tb, fc, sprf, lane);
    else if (wave == 5) produce_terms<36, 45>(rb, tb, fc, sprf, lane);
    else if (wave == 6) produce_terms<45, 53>(rb, tb, fc, sprf, lane);
    else if (wave == 7) produce_terms<53, 61>(rb, tb, fc, sprf, lane);
    if (pre) {
      rowbuf[kb ^ 1][lane] = p0;
      rowbuf[kb ^ 1][lane + 64] = p1;
    }
    __syncthreads();
    if (wave == 0) {
#pragma unroll
      for (int dcu = 0; dcu < 61; ++dcu)
        acc = acc + termbuf[kb][dcu][lane];     // exact reference order
    }
  }
  if (wave == 0) fimg[y * PSTR + x0 + lane + KWIN].w = acc;
}

// ---------------- parent: 8-wave exact-parallel argmin -------------------------
// Window rows block-partitioned across waves in order: wave w's (dr,dc) ranks
// strictly precede wave w+1's. Strict < everywhere reproduces the reference's
// first-in-row-major tie-break exactly. No fp reassociation.
__global__ __launch_bounds__(512, 4)
void k_par(const float4* __restrict__ pf, int* __restrict__ parent) {
#pragma clang fp contract(off)
  __shared__ float4 prow[8][2][128];
  __shared__ float m_d[8][64];
  __shared__ int   m_p[8][64];
  int tid = threadIdx.x, lane = tid & 63, wave = tid >> 6;
  int b = blockIdx.x;
  int tile = b & 1, y = (b >> 1) & 127, img = b >> 8;
  int x0 = tile * 64, x = x0 + lane;
  const float4* fimg = pf + img * PIMG;
  float4 fc = fimg[y * PSTR + x + KWIN];
  float dcen = fc.w;
  int ny0 = y - KWIN; if (ny0 < 0) ny0 = 0;
  int ny1 = y + KWIN; if (ny1 > H - 1) ny1 = H - 1;
  int nrows = ny1 - ny0 + 1;
  int chunk = (nrows + 7) >> 3;
  int rb = ny0 + wave * chunk;
  int re = rb + chunk; if (re > ny1 + 1) re = ny1 + 1;
  float bestd = __builtin_inff();
  int bestp = y * W + x;
  if (rb < re) {
    const float4* row = fimg + rb * PSTR + x0;
    prow[wave][0][lane] = row[lane];
    prow[wave][0][lane + 64] = row[lane + 64];
    int cur = 0;
    for (int ny = rb; ny < re; ++ny) {
      float4 p0, p1;
      if (ny + 1 < re) {
        const float4* nrow = fimg + (ny + 1) * PSTR + x0;
        p0 = nrow[lane];
        p1 = nrow[lane + 64];
      }
      int dr = ny - y;
      float sprf = (float)(dr * dr);
      int qbase = ny * W + x;
#pragma unroll
      for (int dcu = 0; dcu < 61; ++dcu) {
        float4 nb = prow[wave][cur][lane + dcu];
        float nd = nb.w;                   // pad cols: -inf, never qualifies
        float d0 = fc.x - nb.x, d1 = fc.y - nb.y, d2 = fc.z - nb.z;
        float d = (d0 * d0 + d1 * d1) + d2 * d2;
        float cdc = (float)((dcu - KWIN) * (dcu - KWIN));
        d = d + (sprf + cdc);              // exact (ints < 2^11)
        int better = (nd > dcen) & (d < bestd);
        bestd = better ? d : bestd;
        bestp = better ? (qbase + (dcu - KWIN)) : bestp;
      }
      if (ny + 1 < re) {
        prow[wave][cur ^ 1][lane] = p0;
        prow[wave][cur ^ 1][lane + 64] = p1;
        cur ^= 1;
      }
    }
  }
  m_d[wave][lane] = bestd;
  m_p[wave][lane] = bestp;
  __syncthreads();
  if (wave == 0) {
    for (int w = 1; w < 8; ++w) {
      float dw = m_d[w][lane];
      int pw = m_p[w][lane];
      int better = dw < bestd;             // ties keep earlier wave = lower rank
      bestd = better ? dw : bestd;
      bestp = better ? pw : bestp;
    }
    if (bestd > 400.0f) bestp = y * W + x; // sqrt(best_d) > max_dist
    parent[img * NP + y * W + x] = bestp;
  }
}

// ---------------- root chase + presence marking --------------------------------
__global__ void k_root(const int* __restrict__ parent, int* __restrict__ root,
                       int* __restrict__ pres) {
  int i = blockIdx.x * blockDim.x + threadIdx.x;
  if (i >= IMGS * NP) return;
  int img = i / NP, p = i % NP;
  const int* par = parent + img * NP;
  int r = par[p];
  for (int it = 0; it < NP; ++it) {        // chains strictly increase density => acyclic
    int pr = par[r];
    if (pr == r) break;
    r = pr;
  }
  root[i] = r;
  pres[img * NP + r] = 1;
}

// ---------------- per-image scan of presence flags + final labels (fused) ------
__global__ void k_scanlabel(const int* __restrict__ root, int* __restrict__ pres,
                            int* __restrict__ out) {
  __shared__ int part[256];
  int img = blockIdx.x;
  int t = threadIdx.x;                     // 256 threads x 64 elements
  int* a = pres + img * NP;
  int base = t * 64;
  int s = 0;
  for (int j = 0; j < 64; ++j) s += a[base + j];
  part[t] = s;
  __syncthreads();
  for (int off = 1; off < 256; off <<= 1) {
    int add = (t >= off) ? part[t - off] : 0;
    __syncthreads();
    part[t] += add;
    __syncthreads();
  }
  int run = part[t] - s;
  for (int j = 0; j < 64; ++j) {
    run += a[base + j];
    a[base + j] = run;
  }
  __syncthreads();
  const int* rimg = root + img * NP;
  int* oimg = out + img * NP;
  for (int j = t; j < NP; j += 256) {
    int lab = a[rimg[j]] - 1;
    oimg[j] = (lab < MAXSEG - 1) ? lab : (MAXSEG - 1);
  }
}

extern "C" void kernel_launch(void* const* d_in, const int* in_sizes, int n_in,
                              void* d_out, int out_size, void* d_ws, size_t ws_size,
                              hipStream_t stream) {
  const float* x = (const float*)d_in[0];
  int* out = (int*)d_out;
  char* ws = (char*)d_ws;

  // workspace layout (~1.75 MB); parent/root/pres alias bufA (dead after blurV).
  // pres is zeroed via memsetAsync AFTER the blur stages (aliasing-safe order).
  float4* pf   = (float4*)(ws);                         // 2*24576*16 = 786432
  float4* bufA = (float4*)(ws + 786432);                // 524288 (lab out / blurV in)
  float4* bufB = (float4*)(ws + 786432 + 524288);       // 524288 (blurV out / blurH in)
  int* parent  = (int*)(ws + 786432);                   // alias bufA
  int* root    = (int*)(ws + 786432 + 131072);
  int* pres    = (int*)(ws + 786432 + 262144);

  const int total = IMGS * NP;                          // 32768
  const int ptotal = IMGS * PIMG;                       // 49152

  k_fill<<<(ptotal + 255) / 256, 256, 0, stream>>>(pf);
  k_lab<<<total / 256, 256, 0, stream>>>(x, bufA);
  k_blurV<<<total / 256, 256, 0, stream>>>(bufA, bufB);
  k_blurH<<<total / 256, 256, 0, stream>>>(bufB, pf);
  k_dens<<<512, 512, 0, stream>>>(pf);
  k_par<<<512, 512, 0, stream>>>(pf, parent);
  hipMemsetAsync(pres, 0, total * sizeof(int), stream);
  k_root<<<total / 256, 256, 0, stream>>>(parent, root, pres);
  k_scanlabel<<<IMGS, 256, 0, stream>>>(root, pres, out);
}

// Round 7
// 238.506 us; speedup vs baseline: 2.1423x; 1.0163x over previous
//
#include <hip/hip_runtime.h>
#include <math.h>

static constexpr int IMGS = 2;
static constexpr int H = 128, W = 128;
static constexpr int NP = H * W;           // 16384
static constexpr int KWIN = 30;            // quickshift window radius (ceil(3*10))
static constexpr int GR = 20;              // gaussian radius int(4*5+0.5)
static constexpr float INV = 0.005f;       // 0.5 / (10*10)
static constexpr int MAXSEG = 40;

// padded feature layout: row stride 192 float4, cols [30,158) hold the image.
// float4 = (L, a, b, dens); pads = (1e6,1e6,1e6,-inf).
static constexpr int PSTR = 192;
static constexpr int PIMG = H * PSTR;      // 24576 float4 per image

// ---------------- prep: pf sentinel fill + rgb2lab into bufL -------------------
// pf pads: xyz=1e6 (exp term -> exact +0.0), .w=-inf (density pad).
// lab math identical to rounds 1-6 (absmax 0.0) — do not touch.
__global__ void k_prep(const float* __restrict__ x, float4* __restrict__ pf,
                       float4* __restrict__ bufL) {
#pragma clang fp contract(off)
  int i = blockIdx.x * blockDim.x + threadIdx.x;
  if (i < IMGS * PIMG) pf[i] = make_float4(1e6f, 1e6f, 1e6f, -__builtin_inff());
  if (i >= IMGS * NP) return;
  int img = i / NP, p = i % NP;
  const float* base = x + img * 3 * NP;
  float rgb[3] = { base[p], base[NP + p], base[2 * NP + p] };
  float lin[3];
  for (int c = 0; c < 3; ++c) {
    float v = rgb[c];
    lin[c] = (v > 0.04045f) ? powf((v + 0.055f) / 1.055f, 2.4f) : (v / 12.92f);
  }
  const float M[3][3] = {{0.412453f, 0.357580f, 0.180423f},
                         {0.212671f, 0.715160f, 0.072169f},
                         {0.019334f, 0.119193f, 0.950227f}};
  const float wp[3] = {0.95047f, 1.0f, 1.08883f};
  float f[3];
  for (int j = 0; j < 3; ++j) {
    float s = lin[0] * M[j][0];
    s = s + lin[1] * M[j][1];
    s = s + lin[2] * M[j][2];
    float xyz = s / wp[j];
    f[j] = (xyz > 0.008856f) ? cbrtf(fmaxf(xyz, 1e-8f))
                             : (7.787f * xyz + (float)(16.0 / 116.0));
  }
  float L = 116.0f * f[1] - 16.0f;
  float a = 500.0f * (f[0] - f[1]);
  float b = 200.0f * (f[1] - f[2]);
  bufL[i] = make_float4(L, a, b, 0.0f);
}

// ---------------- fused separable gaussian (V then H), symmetric pad -----------
// block = one image row; 384 threads = (channel, col). Vertical 41-tap from
// bufL (per-channel chain, exact ref order), row result staged in LDS, then
// horizontal 41-tap from LDS, scalar component store into padded pf interior.
// Channels were always independent accumulators in the reference — identical
// per-channel op order. Weight computation identical to rounds 1-6.
__global__ __launch_bounds__(384)
void k_blur(const float4* __restrict__ bufL, float4* __restrict__ pf) {
#pragma clang fp contract(off)
  __shared__ float w[2 * GR + 1];
  __shared__ float mid[3][128];
  if (threadIdx.x == 0) {
    double k[2 * GR + 1];
    double s = 0.0;
    for (int i = -GR; i <= GR; ++i) {
      double t = (double)i / 5.0;
      double v = exp(-0.5 * t * t);
      k[i + GR] = v;
      s += v;
    }
    for (int i = 0; i < 2 * GR + 1; ++i) w[i] = (float)(k[i] / s);
  }
  __syncthreads();
  int tid = threadIdx.x;
  int c = tid >> 7;                         // 0..2
  int xx = tid & 127;
  int b = blockIdx.x;                       // img*128 + y
  int y = b & 127, img = b >> 7;
  const float* base = (const float*)(bufL + img * NP);  // component c of px p at base[4p+c]
  float a = 0.0f;
  for (int t = 0; t <= 2 * GR; ++t) {
    int yy = y - GR + t;
    if (yy < 0) yy = -yy - 1;
    if (yy >= H) yy = 2 * H - 1 - yy;
    a = a + w[t] * base[(yy * W + xx) * 4 + c];
  }
  mid[c][xx] = a;
  __syncthreads();
  float o = 0.0f;
  for (int t = 0; t <= 2 * GR; ++t) {
    int xq = xx - GR + t;
    if (xq < 0) xq = -xq - 1;
    if (xq >= W) xq = 2 * W - 1 - xq;
    o = o + w[t] * mid[c][xq];
  }
  ((float*)(pf + img * PIMG + y * PSTR + xx + KWIN))[c] = o;  // 4B store, no race
}

// ---------------- density: 8-wave producer/folder, exact sequential fold -------
// wave0: folds each row's 61 terms in exact (row, dc) order.
// waves 1..7: produce dc-chunks 9/9/9/9/9/8/8 (template-unrolled, immediate
// LDS offsets). wave7 also prefetches the next feature row.
// Double-buffered rowbuf+termbuf, one barrier per row — race-free: producers
// can only overwrite termbuf[k&1] after barrier k+1, which wave0 reaches only
// after fold(k); rowbuf[kb^1] is written before barrier k and read after it.
template<int DB, int DE>
__device__ inline void produce_terms(const float4* __restrict__ rb,
                                     float* __restrict__ tb,
                                     float4 fc, float sprf, int lane) {
#pragma clang fp contract(off)
#pragma unroll
  for (int dcu = DB; dcu < DE; ++dcu) {
    float4 nb = rb[lane + dcu];
    float d0 = fc.x - nb.x, d1 = fc.y - nb.y, d2 = fc.z - nb.z;
    float d = (d0 * d0 + d1 * d1) + d2 * d2;
    float cdc = (float)((dcu - KWIN) * (dcu - KWIN));
    d = d + (sprf + cdc);                 // exact: both ints < 2^11, sum exact
    tb[dcu * 64 + lane] = expf(-d * INV); // pad cols -> exact +0.0
  }
}

__global__ __launch_bounds__(512, 4)
void k_dens(float4* __restrict__ pf) {
#pragma clang fp contract(off)
  __shared__ float4 rowbuf[2][128];
  __shared__ float termbuf[2][61][64];
  int tid = threadIdx.x;
  int lane = tid & 63;
  int wave = tid >> 6;
  int b = blockIdx.x;                      // 512 blocks: img*256 + y*2 + tile
  int tile = b & 1, y = (b >> 1) & 127, img = b >> 8;
  int x0 = tile * 64;
  float4* fimg = pf + img * PIMG;
  float4 fc = fimg[y * PSTR + x0 + lane + KWIN];
  int ny0 = y - KWIN; if (ny0 < 0) ny0 = 0;
  int ny1 = y + KWIN; if (ny1 > H - 1) ny1 = H - 1;
  if (wave == 7) {
    const float4* row = fimg + ny0 * PSTR + x0;
    rowbuf[0][lane] = row[lane];
    rowbuf[0][lane + 64] = row[lane + 64];
  }
  __syncthreads();
  float acc = 0.0f;
  for (int ny = ny0; ny <= ny1; ++ny) {    // skipped rows: ref adds exact 0.0
    int kb = (ny - ny0) & 1;
    float4 p0, p1;
    bool pre = (wave == 7) && (ny < ny1);
    if (pre) {                             // issue prefetch early
      const float4* nrow = fimg + (ny + 1) * PSTR + x0;
      p0 = nrow[lane];
      p1 = nrow[lane + 64];
    }
    int dr = ny - y;
    float sprf = (float)(dr * dr);
    const float4* rb = rowbuf[kb];
    float* tb = &termbuf[kb][0][0];
    if      (wave == 1) produce_terms< 0,  9>(rb, tb, fc, sprf, lane);
    else if (wave == 2) produce_terms< 9, 18>(rb, tb, fc, sprf, lane);
    else if (wave == 3) produce_terms<18, 27>(rb, tb, fc, sprf, lane);
    else if (wave == 4) produce_terms<27, 36>(rb, tb, fc, sprf, lane);
    else if (wave == 5) produce_terms<36, 45>(rb, tb, fc, sprf, lane);
    else if (wave == 6) produce_terms<45, 53>(rb, tb, fc, sprf, lane);
    else if (wave == 7) produce_terms<53, 61>(rb, tb, fc, sprf, lane);
    if (pre) {
      rowbuf[kb ^ 1][lane] = p0;
      rowbuf[kb ^ 1][lane + 64] = p1;
    }
    __syncthreads();
    if (wave == 0) {
#pragma unroll
      for (int dcu = 0; dcu < 61; ++dcu)
        acc = acc + termbuf[kb][dcu][lane];     // exact reference order
    }
  }
  if (wave == 0) fimg[y * PSTR + x0 + lane + KWIN].w = acc;
}

// ---------------- parent: 8-wave exact-parallel argmin + pres zeroing ----------
// Window rows block-partitioned across waves in order: wave w's (dr,dc) ranks
// strictly precede wave w+1's. Strict < everywhere reproduces the reference's
// first-in-row-major tie-break exactly. No fp reassociation.
// Each block also zeros its own 64 pres entries (replaces the memset launch;
// pres no longer aliases any live buffer).
__global__ __launch_bounds__(512, 4)
void k_par(const float4* __restrict__ pf, int* __restrict__ parent,
           int* __restrict__ pres) {
#pragma clang fp contract(off)
  __shared__ float4 prow[8][2][128];
  __shared__ float m_d[8][64];
  __shared__ int   m_p[8][64];
  int tid = threadIdx.x, lane = tid & 63, wave = tid >> 6;
  int b = blockIdx.x;
  int tile = b & 1, y = (b >> 1) & 127, img = b >> 8;
  int x0 = tile * 64, x = x0 + lane;
  if (wave == 1) pres[img * NP + y * W + x] = 0;
  const float4* fimg = pf + img * PIMG;
  float4 fc = fimg[y * PSTR + x + KWIN];
  float dcen = fc.w;
  int ny0 = y - KWIN; if (ny0 < 0) ny0 = 0;
  int ny1 = y + KWIN; if (ny1 > H - 1) ny1 = H - 1;
  int nrows = ny1 - ny0 + 1;
  int chunk = (nrows + 7) >> 3;
  int rb = ny0 + wave * chunk;
  int re = rb + chunk; if (re > ny1 + 1) re = ny1 + 1;
  float bestd = __builtin_inff();
  int bestp = y * W + x;
  if (rb < re) {
    const float4* row = fimg + rb * PSTR + x0;
    prow[wave][0][lane] = row[lane];
    prow[wave][0][lane + 64] = row[lane + 64];
    int cur = 0;
    for (int ny = rb; ny < re; ++ny) {
      float4 p0, p1;
      if (ny + 1 < re) {
        const float4* nrow = fimg + (ny + 1) * PSTR + x0;
        p0 = nrow[lane];
        p1 = nrow[lane + 64];
      }
      int dr = ny - y;
      float sprf = (float)(dr * dr);
      int qbase = ny * W + x;
#pragma unroll
      for (int dcu = 0; dcu < 61; ++dcu) {
        float4 nb = prow[wave][cur][lane + dcu];
        float nd = nb.w;                   // pad cols: -inf, never qualifies
        float d0 = fc.x - nb.x, d1 = fc.y - nb.y, d2 = fc.z - nb.z;
        float d = (d0 * d0 + d1 * d1) + d2 * d2;
        float cdc = (float)((dcu - KWIN) * (dcu - KWIN));
        d = d + (sprf + cdc);              // exact (ints < 2^11)
        int better = (nd > dcen) & (d < bestd);
        bestd = better ? d : bestd;
        bestp = better ? (qbase + (dcu - KWIN)) : bestp;
      }
      if (ny + 1 < re) {
        prow[wave][cur ^ 1][lane] = p0;
        prow[wave][cur ^ 1][lane + 64] = p1;
        cur ^= 1;
      }
    }
  }
  m_d[wave][lane] = bestd;
  m_p[wave][lane] = bestp;
  __syncthreads();
  if (wave == 0) {
    for (int w = 1; w < 8; ++w) {
      float dw = m_d[w][lane];
      int pw = m_p[w][lane];
      int better = dw < bestd;             // ties keep earlier wave = lower rank
      bestd = better ? dw : bestd;
      bestp = better ? pw : bestp;
    }
    if (bestd > 400.0f) bestp = y * W + x; // sqrt(best_d) > max_dist
    parent[img * NP + y * W + x] = bestp;
  }
}

// ---------------- root chase + presence marking --------------------------------
__global__ void k_root(const int* __restrict__ parent, int* __restrict__ root,
                       int* __restrict__ pres) {
  int i = blockIdx.x * blockDim.x + threadIdx.x;
  if (i >= IMGS * NP) return;
  int img = i / NP, p = i % NP;
  const int* par = parent + img * NP;
  int r = par[p];
  for (int it = 0; it < NP; ++it) {        // chains strictly increase density => acyclic
    int pr = par[r];
    if (pr == r) break;
    r = pr;
  }
  root[i] = r;
  pres[img * NP + r] = 1;
}

// ---------------- per-image scan of presence flags + final labels (fused) ------
__global__ void k_scanlabel(const int* __restrict__ root, int* __restrict__ pres,
                            int* __restrict__ out) {
  __shared__ int part[256];
  int img = blockIdx.x;
  int t = threadIdx.x;                     // 256 threads x 64 elements
  int* a = pres + img * NP;
  int base = t * 64;
  int s = 0;
  for (int j = 0; j < 64; ++j) s += a[base + j];
  part[t] = s;
  __syncthreads();
  for (int off = 1; off < 256; off <<= 1) {
    int add = (t >= off) ? part[t - off] : 0;
    __syncthreads();
    part[t] += add;
    __syncthreads();
  }
  int run = part[t] - s;
  for (int j = 0; j < 64; ++j) {
    run += a[base + j];
    a[base + j] = run;
  }
  __syncthreads();
  const int* rimg = root + img * NP;
  int* oimg = out + img * NP;
  for (int j = t; j < NP; j += 256) {
    int lab = a[rimg[j]] - 1;
    oimg[j] = (lab < MAXSEG - 1) ? lab : (MAXSEG - 1);
  }
}

extern "C" void kernel_launch(void* const* d_in, const int* in_sizes, int n_in,
                              void* d_out, int out_size, void* d_ws, size_t ws_size,
                              hipStream_t stream) {
  const float* x = (const float*)d_in[0];
  int* out = (int*)d_out;
  char* ws = (char*)d_ws;

  // workspace layout (~1.63 MB), no aliasing anywhere:
  float4* pf   = (float4*)(ws);                         // 2*24576*16 = 786432
  float4* bufL = (float4*)(ws + 786432);                // 524288 (lab output)
  int* parent  = (int*)(ws + 1310720);                  // 131072
  int* root    = (int*)(ws + 1441792);                  // 131072
  int* pres    = (int*)(ws + 1572864);                  // 131072 (zeroed in k_par)

  const int total = IMGS * NP;                          // 32768
  const int ptotal = IMGS * PIMG;                       // 49152

  k_prep<<<(ptotal + 255) / 256, 256, 0, stream>>>(x, pf, bufL);
  k_blur<<<IMGS * H, 384, 0, stream>>>(bufL, pf);
  k_dens<<<512, 512, 0, stream>>>(pf);
  k_par<<<512, 512, 0, stream>>>(pf, parent, pres);
  k_root<<<total / 256, 256, 0, stream>>>(parent, root, pres);
  k_scanlabel<<<IMGS, 256, 0, stream>>>(root, pres, out);
}

// Round 8
// 216.319 us; speedup vs baseline: 2.3621x; 1.1026x over previous
//
#include <hip/hip_runtime.h>
#include <math.h>

static constexpr int IMGS = 2;
static constexpr int H = 128, W = 128;
static constexpr int NP = H * W;           // 16384
static constexpr int KWIN = 30;            // quickshift window radius (ceil(3*10))
static constexpr int GR = 20;              // gaussian radius int(4*5+0.5)
static constexpr float INV = 0.005f;       // 0.5 / (10*10)
static constexpr int MAXSEG = 40;

// padded feature layout: row stride 192 float4, cols [30,158) hold the image.
// float4 = (L, a, b, dens); pads = (1e6,1e6,1e6,-inf).
static constexpr int PSTR = 192;
static constexpr int PIMG = H * PSTR;      // 24576 float4 per image

// ---------------- prep: pf sentinel fill + rgb2lab into bufL -------------------
__global__ void k_prep(const float* __restrict__ x, float4* __restrict__ pf,
                       float4* __restrict__ bufL) {
#pragma clang fp contract(off)
  int i = blockIdx.x * blockDim.x + threadIdx.x;
  if (i < IMGS * PIMG) pf[i] = make_float4(1e6f, 1e6f, 1e6f, -__builtin_inff());
  if (i >= IMGS * NP) return;
  int img = i / NP, p = i % NP;
  const float* base = x + img * 3 * NP;
  float rgb[3] = { base[p], base[NP + p], base[2 * NP + p] };
  float lin[3];
  for (int c = 0; c < 3; ++c) {
    float v = rgb[c];
    lin[c] = (v > 0.04045f) ? powf((v + 0.055f) / 1.055f, 2.4f) : (v / 12.92f);
  }
  const float M[3][3] = {{0.412453f, 0.357580f, 0.180423f},
                         {0.212671f, 0.715160f, 0.072169f},
                         {0.019334f, 0.119193f, 0.950227f}};
  const float wp[3] = {0.95047f, 1.0f, 1.08883f};
  float f[3];
  for (int j = 0; j < 3; ++j) {
    float s = lin[0] * M[j][0];
    s = s + lin[1] * M[j][1];
    s = s + lin[2] * M[j][2];
    float xyz = s / wp[j];
    f[j] = (xyz > 0.008856f) ? cbrtf(fmaxf(xyz, 1e-8f))
                             : (7.787f * xyz + (float)(16.0 / 116.0));
  }
  float L = 116.0f * f[1] - 16.0f;
  float a = 500.0f * (f[0] - f[1]);
  float b = 200.0f * (f[1] - f[2]);
  bufL[i] = make_float4(L, a, b, 0.0f);
}

// ---------------- fused separable gaussian (V then H), symmetric pad -----------
__global__ __launch_bounds__(384)
void k_blur(const float4* __restrict__ bufL, float4* __restrict__ pf) {
#pragma clang fp contract(off)
  __shared__ float w[2 * GR + 1];
  __shared__ float mid[3][128];
  if (threadIdx.x == 0) {
    double k[2 * GR + 1];
    double s = 0.0;
    for (int i = -GR; i <= GR; ++i) {
      double t = (double)i / 5.0;
      double v = exp(-0.5 * t * t);
      k[i + GR] = v;
      s += v;
    }
    for (int i = 0; i < 2 * GR + 1; ++i) w[i] = (float)(k[i] / s);
  }
  __syncthreads();
  int tid = threadIdx.x;
  int c = tid >> 7;                         // 0..2
  int xx = tid & 127;
  int b = blockIdx.x;                       // img*128 + y
  int y = b & 127, img = b >> 7;
  const float* base = (const float*)(bufL + img * NP);
  float a = 0.0f;
  for (int t = 0; t <= 2 * GR; ++t) {
    int yy = y - GR + t;
    if (yy < 0) yy = -yy - 1;
    if (yy >= H) yy = 2 * H - 1 - yy;
    a = a + w[t] * base[(yy * W + xx) * 4 + c];
  }
  mid[c][xx] = a;
  __syncthreads();
  float o = 0.0f;
  for (int t = 0; t <= 2 * GR; ++t) {
    int xq = xx - GR + t;
    if (xq < 0) xq = -xq - 1;
    if (xq >= W) xq = 2 * W - 1 - xq;
    o = o + w[t] * mid[c][xq];
  }
  ((float*)(pf + img * PIMG + y * PSTR + xx + KWIN))[c] = o;  // 4B store, no race
}

// ---------------- density: 8-wave producer/folder, exact sequential fold -------
// R7 change: __expf (native v_exp_f32) replaces ocml expf — ~1e-6 rel dens
// perturbation, self-consistent across all comparisons; pad sentinel still
// underflows to exact +0.0 (arg ~ -2e10). If absmax>0 this is the revert point.
template<int DB, int DE>
__device__ inline void produce_terms(const float4* __restrict__ rb,
                                     float* __restrict__ tb,
                                     float4 fc, float sprf, int lane) {
#pragma clang fp contract(off)
#pragma unroll
  for (int dcu = DB; dcu < DE; ++dcu) {
    float4 nb = rb[lane + dcu];
    float d0 = fc.x - nb.x, d1 = fc.y - nb.y, d2 = fc.z - nb.z;
    float d = (d0 * d0 + d1 * d1) + d2 * d2;
    float cdc = (float)((dcu - KWIN) * (dcu - KWIN));
    d = d + (sprf + cdc);                 // exact: both ints < 2^11, sum exact
    tb[dcu * 64 + lane] = __expf(-d * INV); // pad cols -> exact +0.0
  }
}

__global__ __launch_bounds__(512, 4)
void k_dens(float4* __restrict__ pf) {
#pragma clang fp contract(off)
  __shared__ float4 rowbuf[2][128];
  __shared__ float termbuf[2][61][64];
  int tid = threadIdx.x;
  int lane = tid & 63;
  int wave = tid >> 6;
  int b = blockIdx.x;                      // 512 blocks: img*256 + y*2 + tile
  int tile = b & 1, y = (b >> 1) & 127, img = b >> 8;
  int x0 = tile * 64;
  float4* fimg = pf + img * PIMG;
  float4 fc = fimg[y * PSTR + x0 + lane + KWIN];
  int ny0 = y - KWIN; if (ny0 < 0) ny0 = 0;
  int ny1 = y + KWIN; if (ny1 > H - 1) ny1 = H - 1;
  if (wave == 7) {
    const float4* row = fimg + ny0 * PSTR + x0;
    rowbuf[0][lane] = row[lane];
    rowbuf[0][lane + 64] = row[lane + 64];
  }
  __syncthreads();
  float acc = 0.0f;
  for (int ny = ny0; ny <= ny1; ++ny) {    // skipped rows: ref adds exact 0.0
    int kb = (ny - ny0) & 1;
    float4 p0, p1;
    bool pre = (wave == 7) && (ny < ny1);
    if (pre) {                             // issue prefetch early
      const float4* nrow = fimg + (ny + 1) * PSTR + x0;
      p0 = nrow[lane];
      p1 = nrow[lane + 64];
    }
    int dr = ny - y;
    float sprf = (float)(dr * dr);
    const float4* rb = rowbuf[kb];
    float* tb = &termbuf[kb][0][0];
    if      (wave == 1) produce_terms< 0,  9>(rb, tb, fc, sprf, lane);
    else if (wave == 2) produce_terms< 9, 18>(rb, tb, fc, sprf, lane);
    else if (wave == 3) produce_terms<18, 27>(rb, tb, fc, sprf, lane);
    else if (wave == 4) produce_terms<27, 36>(rb, tb, fc, sprf, lane);
    else if (wave == 5) produce_terms<36, 45>(rb, tb, fc, sprf, lane);
    else if (wave == 6) produce_terms<45, 53>(rb, tb, fc, sprf, lane);
    else if (wave == 7) produce_terms<53, 61>(rb, tb, fc, sprf, lane);
    if (pre) {
      rowbuf[kb ^ 1][lane] = p0;
      rowbuf[kb ^ 1][lane + 64] = p1;
    }
    __syncthreads();
    if (wave == 0) {
#pragma unroll
      for (int dcu = 0; dcu < 61; ++dcu)
        acc = acc + termbuf[kb][dcu][lane];     // exact reference order
    }
  }
  if (wave == 0) fimg[y * PSTR + x0 + lane + KWIN].w = acc;
}

// ---------------- parent: 8-wave exact-parallel argmin, hybrid LDS/L1 ----------
// R7 change: dcu 0..30 read the staged LDS row; dcu 31..60 re-read the same
// row via global loads (L1-hit: the staging load fetched those lines).
// Identical values & order — splits read traffic across LDS and vmem pipes.
__global__ __launch_bounds__(512, 4)
void k_par(const float4* __restrict__ pf, int* __restrict__ parent,
           int* __restrict__ pres) {
#pragma clang fp contract(off)
  __shared__ float4 prow[8][2][128];
  __shared__ float m_d[8][64];
  __shared__ int   m_p[8][64];
  int tid = threadIdx.x, lane = tid & 63, wave = tid >> 6;
  int b = blockIdx.x;
  int tile = b & 1, y = (b >> 1) & 127, img = b >> 8;
  int x0 = tile * 64, x = x0 + lane;
  if (wave == 1) pres[img * NP + y * W + x] = 0;
  const float4* fimg = pf + img * PIMG;
  float4 fc = fimg[y * PSTR + x + KWIN];
  float dcen = fc.w;
  int ny0 = y - KWIN; if (ny0 < 0) ny0 = 0;
  int ny1 = y + KWIN; if (ny1 > H - 1) ny1 = H - 1;
  int nrows = ny1 - ny0 + 1;
  int chunk = (nrows + 7) >> 3;
  int rb = ny0 + wave * chunk;
  int re = rb + chunk; if (re > ny1 + 1) re = ny1 + 1;
  float bestd = __builtin_inff();
  int bestp = y * W + x;
  if (rb < re) {
    const float4* row = fimg + rb * PSTR + x0;
    prow[wave][0][lane] = row[lane];
    prow[wave][0][lane + 64] = row[lane + 64];
    int cur = 0;
    for (int ny = rb; ny < re; ++ny) {
      float4 p0, p1;
      if (ny + 1 < re) {
        const float4* nrow = fimg + (ny + 1) * PSTR + x0;
        p0 = nrow[lane];
        p1 = nrow[lane + 64];
      }
      int dr = ny - y;
      float sprf = (float)(dr * dr);
      int qbase = ny * W + x;
      const float4* grow = fimg + ny * PSTR + x0;   // L1-resident (just staged)
#pragma unroll
      for (int dcu = 0; dcu < 61; ++dcu) {
        float4 nb = (dcu < 31) ? prow[wave][cur][lane + dcu]   // LDS pipe
                               : grow[lane + dcu];             // vmem pipe (L1)
        float nd = nb.w;                   // pad cols: -inf, never qualifies
        float d0 = fc.x - nb.x, d1 = fc.y - nb.y, d2 = fc.z - nb.z;
        float d = (d0 * d0 + d1 * d1) + d2 * d2;
        float cdc = (float)((dcu - KWIN) * (dcu - KWIN));
        d = d + (sprf + cdc);              // exact (ints < 2^11)
        int better = (nd > dcen) & (d < bestd);
        bestd = better ? d : bestd;
        bestp = better ? (qbase + (dcu - KWIN)) : bestp;
      }
      if (ny + 1 < re) {
        prow[wave][cur ^ 1][lane] = p0;
        prow[wave][cur ^ 1][lane + 64] = p1;
        cur ^= 1;
      }
    }
  }
  m_d[wave][lane] = bestd;
  m_p[wave][lane] = bestp;
  __syncthreads();
  if (wave == 0) {
    for (int w = 1; w < 8; ++w) {
      float dw = m_d[w][lane];
      int pw = m_p[w][lane];
      int better = dw < bestd;             // ties keep earlier wave = lower rank
      bestd = better ? dw : bestd;
      bestp = better ? pw : bestp;
    }
    if (bestd > 400.0f) bestp = y * W + x; // sqrt(best_d) > max_dist
    parent[img * NP + y * W + x] = bestp;
  }
}

// ---------------- root chase + presence marking --------------------------------
__global__ void k_root(const int* __restrict__ parent, int* __restrict__ root,
                       int* __restrict__ pres) {
  int i = blockIdx.x * blockDim.x + threadIdx.x;
  if (i >= IMGS * NP) return;
  int img = i / NP, p = i % NP;
  const int* par = parent + img * NP;
  int r = par[p];
  for (int it = 0; it < NP; ++it) {        // chains strictly increase density => acyclic
    int pr = par[r];
    if (pr == r) break;
    r = pr;
  }
  root[i] = r;
  pres[img * NP + r] = 1;
}

// ---------------- per-image scan of presence flags + final labels (fused) ------
__global__ void k_scanlabel(const int* __restrict__ root, int* __restrict__ pres,
                            int* __restrict__ out) {
  __shared__ int part[256];
  int img = blockIdx.x;
  int t = threadIdx.x;                     // 256 threads x 64 elements
  int* a = pres + img * NP;
  int base = t * 64;
  int s = 0;
  for (int j = 0; j < 64; ++j) s += a[base + j];
  part[t] = s;
  __syncthreads();
  for (int off = 1; off < 256; off <<= 1) {
    int add = (t >= off) ? part[t - off] : 0;
    __syncthreads();
    part[t] += add;
    __syncthreads();
  }
  int run = part[t] - s;
  for (int j = 0; j < 64; ++j) {
    run += a[base + j];
    a[base + j] = run;
  }
  __syncthreads();
  const int* rimg = root + img * NP;
  int* oimg = out + img * NP;
  for (int j = t; j < NP; j += 256) {
    int lab = a[rimg[j]] - 1;
    oimg[j] = (lab < MAXSEG - 1) ? lab : (MAXSEG - 1);
  }
}

extern "C" void kernel_launch(void* const* d_in, const int* in_sizes, int n_in,
                              void* d_out, int out_size, void* d_ws, size_t ws_size,
                              hipStream_t stream) {
  const float* x = (const float*)d_in[0];
  int* out = (int*)d_out;
  char* ws = (char*)d_ws;

  // workspace layout (~1.63 MB), no aliasing anywhere:
  float4* pf   = (float4*)(ws);                         // 2*24576*16 = 786432
  float4* bufL = (float4*)(ws + 786432);                // 524288 (lab output)
  int* parent  = (int*)(ws + 1310720);                  // 131072
  int* root    = (int*)(ws + 1441792);                  // 131072
  int* pres    = (int*)(ws + 1572864);                  // 131072 (zeroed in k_par)

  const int total = IMGS * NP;                          // 32768
  const int ptotal = IMGS * PIMG;                       // 49152

  k_prep<<<(ptotal + 255) / 256, 256, 0, stream>>>(x, pf, bufL);
  k_blur<<<IMGS * H, 384, 0, stream>>>(bufL, pf);
  k_dens<<<512, 512, 0, stream>>>(pf);
  k_par<<<512, 512, 0, stream>>>(pf, parent, pres);
  k_root<<<total / 256, 256, 0, stream>>>(parent, root, pres);
  k_scanlabel<<<IMGS, 256, 0, stream>>>(root, pres, out);
}